// Round 1
// baseline (2942.976 us; speedup 1.0000x reference)
//
#include <hip/hip_runtime.h>
#include <math.h>

#define N_NODES 50000
#define N_EDGES 800000
#define FEAT    16
#define HID     64
#define KORD    32
#define NCLS    8

// W[d,k,f,c] flat index = (d*KORD + k)*80*64 + f*64 + c ; only rows f<16 matter (H0==0).
#define WSL     5120   // 80*64, per-(d,k) slice stride in floats

static constexpr size_t Aln(size_t x) { return (x + 255) & ~size_t(255); }

// ---- workspace layout (bytes) ----
static constexpr size_t OFF_DEG_OUT = 0;
static constexpr size_t OFF_DEG_IN  = OFF_DEG_OUT + Aln(N_NODES * 4);
static constexpr size_t OFF_CUR_DST = OFF_DEG_IN  + Aln(N_NODES * 4);
static constexpr size_t OFF_CUR_SRC = OFF_CUR_DST + Aln(N_NODES * 4);
static constexpr size_t ZERO_BYTES  = OFF_CUR_SRC + Aln(N_NODES * 4);   // zero [0, ZERO_BYTES)
static constexpr size_t OFF_OFF_DST = ZERO_BYTES;
static constexpr size_t OFF_OFF_SRC = OFF_OFF_DST + Aln((N_NODES + 1) * 4);
static constexpr size_t OFF_CSRD_S  = OFF_OFF_SRC + Aln((N_NODES + 1) * 4);
static constexpr size_t OFF_CSRD_W  = OFF_CSRD_S  + Aln(N_EDGES * 4);
static constexpr size_t OFF_CSRS_D  = OFF_CSRD_W  + Aln(N_EDGES * 4);
static constexpr size_t OFF_CSRS_W  = OFF_CSRS_D  + Aln(N_EDGES * 4);
static constexpr size_t OFF_TO0     = OFF_CSRS_W  + Aln(N_EDGES * 4);
static constexpr size_t OFF_TO1     = OFF_TO0 + Aln(N_NODES * FEAT * 4);
static constexpr size_t OFF_TI0     = OFF_TO1 + Aln(N_NODES * FEAT * 4);
static constexpr size_t OFF_TI1     = OFF_TI0 + Aln(N_NODES * FEAT * 4);
static constexpr size_t OFF_HZ      = OFF_TI1 + Aln(N_NODES * FEAT * 4);
static constexpr size_t OFF_HH      = OFF_HZ  + Aln(N_NODES * HID * 4);
// total ~52.4 MB

__global__ void count_deg_kernel(const int* __restrict__ ei,
                                 int* __restrict__ deg_out, int* __restrict__ deg_in) {
    int e = blockIdx.x * blockDim.x + threadIdx.x;
    if (e < N_EDGES) {
        atomicAdd(&deg_out[ei[e]], 1);
        atomicAdd(&deg_in[ei[N_EDGES + e]], 1);
    }
}

// two exclusive scans (one block each): block 0: degA->offA, block 1: degB->offB
__global__ __launch_bounds__(1024) void scan_kernel(const int* __restrict__ degA, int* __restrict__ offA,
                                                    const int* __restrict__ degB, int* __restrict__ offB) {
    const int* deg = blockIdx.x ? degB : degA;
    int* off = blockIdx.x ? offB : offA;
    __shared__ int wsum[16];
    __shared__ int s_run;
    const int t = threadIdx.x, lane = t & 63, wid = t >> 6;
    if (t == 0) s_run = 0;
    __syncthreads();
    for (int base = 0; base < N_NODES; base += 1024) {
        int i = base + t;
        int v = (i < N_NODES) ? deg[i] : 0;
        int xv = v;
        #pragma unroll
        for (int d = 1; d < 64; d <<= 1) {
            int tt = __shfl_up(xv, d, 64);
            if (lane >= d) xv += tt;
        }
        if (lane == 63) wsum[wid] = xv;
        __syncthreads();
        int add = s_run;
        for (int w = 0; w < wid; ++w) add += wsum[w];
        if (i < N_NODES) off[i] = add + xv - v;   // exclusive
        __syncthreads();
        if (t == 1023) s_run = add + xv;
        __syncthreads();
    }
    if (t == 0) off[N_NODES] = s_run;
}

__global__ void fill_csr_kernel(const int* __restrict__ ei,
                                const int* __restrict__ deg_out, const int* __restrict__ deg_in,
                                const int* __restrict__ off_dst, const int* __restrict__ off_src,
                                int* __restrict__ cur_dst, int* __restrict__ cur_src,
                                int* __restrict__ csrd_s, float* __restrict__ csrd_w,
                                int* __restrict__ csrs_d, float* __restrict__ csrs_w) {
    int e = blockIdx.x * blockDim.x + threadIdx.x;
    if (e >= N_EDGES) return;
    int s = ei[e], d = ei[N_EDGES + e];
    int p = off_dst[d] + atomicAdd(&cur_dst[d], 1);
    csrd_s[p] = s;
    csrd_w[p] = 1.0f / (float)deg_out[s];   // norm_out[e] = 1/deg_out[src]
    int q = off_src[s] + atomicAdd(&cur_src[s], 1);
    csrs_d[q] = d;
    csrs_w[q] = 1.0f / (float)deg_in[d];    // norm_in[e] = 1/deg_in[dst]
}

// k=0 and k=1 terms: T1o/T1i = P(x); Hz/Hh = b + x@(W[0,0]+W[1,0]) + T1o@W[0,1] + T1i@W[1,1]
__global__ __launch_bounds__(256) void init_kernel(
    const float* __restrict__ x,
    const int* __restrict__ off_dst, const int* __restrict__ csrd_s, const float* __restrict__ csrd_w,
    const int* __restrict__ off_src, const int* __restrict__ csrs_d, const float* __restrict__ csrs_w,
    const float* __restrict__ Wz, const float* __restrict__ bz,
    const float* __restrict__ Wh, const float* __restrict__ bh,
    float* __restrict__ T1o, float* __restrict__ T1i,
    float* __restrict__ Hz, float* __restrict__ Hh) {
    __shared__ float s_x[16][16], s_to[16][16], s_ti[16][16];
    __shared__ float sWz0s[1024], sWz1o[1024], sWz1i[1024];
    __shared__ float sWh0s[1024], sWh1o[1024], sWh1i[1024];
    const int t = threadIdx.x;
    for (int j = t; j < 1024; j += 256) {
        sWz0s[j] = Wz[j] + Wz[KORD * WSL + j];
        sWz1o[j] = Wz[WSL + j];
        sWz1i[j] = Wz[KORD * WSL + WSL + j];
        sWh0s[j] = Wh[j] + Wh[KORD * WSL + j];
        sWh1o[j] = Wh[WSL + j];
        sWh1i[j] = Wh[KORD * WSL + WSL + j];
    }
    const int nl = t >> 4, f = t & 15;
    const int i = blockIdx.x * 16 + nl;
    float xv = x[i * FEAT + f];
    s_x[nl][f] = xv;
    float acc = 0.f;
    for (int e = off_dst[i]; e < off_dst[i + 1]; ++e)
        acc += csrd_w[e] * x[csrd_s[e] * FEAT + f];
    T1o[i * FEAT + f] = acc; s_to[nl][f] = acc;
    float acc2 = 0.f;
    for (int e = off_src[i]; e < off_src[i + 1]; ++e)
        acc2 += csrs_w[e] * x[csrs_d[e] * FEAT + f];
    T1i[i * FEAT + f] = acc2; s_ti[nl][f] = acc2;
    __syncthreads();
    const int n2 = t >> 4, c0 = (t & 15) * 4;
    float hz[4], hh[4];
    #pragma unroll
    for (int j = 0; j < 4; ++j) { hz[j] = bz[c0 + j]; hh[j] = bh[c0 + j]; }
    #pragma unroll
    for (int ff = 0; ff < 16; ++ff) {
        float xvv = s_x[n2][ff], to = s_to[n2][ff], ti = s_ti[n2][ff];
        #pragma unroll
        for (int j = 0; j < 4; ++j) {
            hz[j] += xvv * sWz0s[ff * 64 + c0 + j] + to * sWz1o[ff * 64 + c0 + j] + ti * sWz1i[ff * 64 + c0 + j];
            hh[j] += xvv * sWh0s[ff * 64 + c0 + j] + to * sWh1o[ff * 64 + c0 + j] + ti * sWh1i[ff * 64 + c0 + j];
        }
    }
    const int i2 = blockIdx.x * 16 + n2;
    #pragma unroll
    for (int j = 0; j < 4; ++j) { Hz[i2 * 64 + c0 + j] = hz[j]; Hh[i2 * 64 + c0 + j] = hh[j]; }
}

// one Chebyshev step k (2..31): T_k = 2*P*T_{k-1} - T_{k-2} (both dirs) + accumulate Hz/Hh
__global__ __launch_bounds__(256) void step_kernel(
    const int* __restrict__ off_dst, const int* __restrict__ csrd_s, const float* __restrict__ csrd_w,
    const int* __restrict__ off_src, const int* __restrict__ csrs_d, const float* __restrict__ csrs_w,
    const float* __restrict__ prevO, const float* __restrict__ ppO, float* __restrict__ outO,
    const float* __restrict__ prevI, const float* __restrict__ ppI, float* __restrict__ outI,
    const float* __restrict__ Wz, const float* __restrict__ Wh, int k,
    float* __restrict__ Hz, float* __restrict__ Hh) {
    __shared__ float s_to[16][16], s_ti[16][16];
    __shared__ float sWz0[1024], sWz1[1024], sWh0[1024], sWh1[1024];
    const int t = threadIdx.x;
    const int b0 = k * WSL, b1 = (KORD + k) * WSL;
    for (int j = t; j < 1024; j += 256) {
        sWz0[j] = Wz[b0 + j]; sWz1[j] = Wz[b1 + j];
        sWh0[j] = Wh[b0 + j]; sWh1[j] = Wh[b1 + j];
    }
    const int nl = t >> 4, f = t & 15;
    const int i = blockIdx.x * 16 + nl;
    float acc = 0.f;
    for (int e = off_dst[i]; e < off_dst[i + 1]; ++e)
        acc += csrd_w[e] * prevO[csrd_s[e] * FEAT + f];
    float t2o = 2.f * acc - ppO[i * FEAT + f];
    outO[i * FEAT + f] = t2o; s_to[nl][f] = t2o;
    float acc2 = 0.f;
    for (int e = off_src[i]; e < off_src[i + 1]; ++e)
        acc2 += csrs_w[e] * prevI[csrs_d[e] * FEAT + f];
    float t2i = 2.f * acc2 - ppI[i * FEAT + f];
    outI[i * FEAT + f] = t2i; s_ti[nl][f] = t2i;
    __syncthreads();
    const int n2 = t >> 4, c0 = (t & 15) * 4;
    float hz[4] = {0.f, 0.f, 0.f, 0.f}, hh[4] = {0.f, 0.f, 0.f, 0.f};
    #pragma unroll
    for (int ff = 0; ff < 16; ++ff) {
        float to = s_to[n2][ff], ti = s_ti[n2][ff];
        #pragma unroll
        for (int j = 0; j < 4; ++j) {
            hz[j] += to * sWz0[ff * 64 + c0 + j] + ti * sWz1[ff * 64 + c0 + j];
            hh[j] += to * sWh0[ff * 64 + c0 + j] + ti * sWh1[ff * 64 + c0 + j];
        }
    }
    const int i2 = blockIdx.x * 16 + n2;
    float4* hzp = (float4*)&Hz[i2 * 64 + c0];
    float4 v = *hzp;
    v.x += hz[0]; v.y += hz[1]; v.z += hz[2]; v.w += hz[3];
    *hzp = v;
    float4* hhp = (float4*)&Hh[i2 * 64 + c0];
    float4 w = *hhp;
    w.x += hh[0]; w.y += hh[1]; w.z += hh[2]; w.w += hh[3];
    *hhp = w;
}

// H = (1-sigmoid(Hz))*tanh(Hh); out = relu(H) @ lin_w + lin_b
__global__ __launch_bounds__(256) void final_kernel(
    const float* __restrict__ Hz, const float* __restrict__ Hh,
    const float* __restrict__ lin_w, const float* __restrict__ lin_b,
    float* __restrict__ out) {
    __shared__ float s_h[32][65];
    const int t = threadIdx.x;
    const int base = blockIdx.x * 32;
    #pragma unroll
    for (int r = 0; r < 8; ++r) {
        int idx = r * 256 + t;
        int n = idx >> 6, h = idx & 63;
        int i = base + n;
        float v = 0.f;
        if (i < N_NODES) {
            float z = 1.f / (1.f + __expf(-Hz[i * 64 + h]));
            float ht = tanhf(Hh[i * 64 + h]);
            v = fmaxf(0.f, (1.f - z) * ht);
        }
        s_h[n][h] = v;
    }
    __syncthreads();
    int n = t >> 3, c = t & 7;
    int i = base + n;
    if (i < N_NODES) {
        float acc = lin_b[c];
        #pragma unroll
        for (int h = 0; h < 64; ++h) acc += s_h[n][h] * lin_w[h * 8 + c];
        out[i * NCLS + c] = acc;
    }
}

extern "C" void kernel_launch(void* const* d_in, const int* in_sizes, int n_in,
                              void* d_out, int out_size, void* d_ws, size_t ws_size,
                              hipStream_t stream) {
    const float* x   = (const float*)d_in[0];
    const int*   ei  = (const int*)d_in[1];
    const float* Wz  = (const float*)d_in[2];
    const float* bz  = (const float*)d_in[3];
    // d_in[4] = W_r, d_in[5] = b_r : unused (H0 == 0 makes R irrelevant)
    const float* Wh  = (const float*)d_in[6];
    const float* bh  = (const float*)d_in[7];
    const float* lw  = (const float*)d_in[8];
    const float* lb  = (const float*)d_in[9];
    float* out = (float*)d_out;
    char* ws = (char*)d_ws;

    int*   deg_out = (int*)(ws + OFF_DEG_OUT);
    int*   deg_in  = (int*)(ws + OFF_DEG_IN);
    int*   cur_dst = (int*)(ws + OFF_CUR_DST);
    int*   cur_src = (int*)(ws + OFF_CUR_SRC);
    int*   off_dst = (int*)(ws + OFF_OFF_DST);
    int*   off_src = (int*)(ws + OFF_OFF_SRC);
    int*   csrd_s  = (int*)(ws + OFF_CSRD_S);
    float* csrd_w  = (float*)(ws + OFF_CSRD_W);
    int*   csrs_d  = (int*)(ws + OFF_CSRS_D);
    float* csrs_w  = (float*)(ws + OFF_CSRS_W);
    float* To0 = (float*)(ws + OFF_TO0);
    float* To1 = (float*)(ws + OFF_TO1);
    float* Ti0 = (float*)(ws + OFF_TI0);
    float* Ti1 = (float*)(ws + OFF_TI1);
    float* Hz  = (float*)(ws + OFF_HZ);
    float* Hh  = (float*)(ws + OFF_HH);

    hipMemsetAsync(ws, 0, ZERO_BYTES, stream);

    const int EB = (N_EDGES + 255) / 256;       // 3125
    const int NB16 = N_NODES / 16;              // 3125 (exact)
    count_deg_kernel<<<EB, 256, 0, stream>>>(ei, deg_out, deg_in);
    scan_kernel<<<2, 1024, 0, stream>>>(deg_in, off_dst, deg_out, off_src);
    fill_csr_kernel<<<EB, 256, 0, stream>>>(ei, deg_out, deg_in, off_dst, off_src,
                                            cur_dst, cur_src, csrd_s, csrd_w, csrs_d, csrs_w);
    init_kernel<<<NB16, 256, 0, stream>>>(x, off_dst, csrd_s, csrd_w, off_src, csrs_d, csrs_w,
                                          Wz, bz, Wh, bh, To1, Ti1, Hz, Hh);
    const float* pO = To1;
    const float* pI = Ti1;
    for (int k = 2; k < KORD; ++k) {
        float* oO = (k & 1) ? To1 : To0;
        float* oI = (k & 1) ? Ti1 : Ti0;
        const float* qO = (k == 2) ? x : (const float*)oO;  // T_{k-2} aliases out buffer (elementwise-safe)
        const float* qI = (k == 2) ? x : (const float*)oI;
        step_kernel<<<NB16, 256, 0, stream>>>(off_dst, csrd_s, csrd_w, off_src, csrs_d, csrs_w,
                                              pO, qO, oO, pI, qI, oI, Wz, Wh, k, Hz, Hh);
        pO = oO; pI = oI;
    }
    final_kernel<<<(N_NODES + 31) / 32, 256, 0, stream>>>(Hz, Hh, lw, lb, out);
}

// Round 2
// 1427.562 us; speedup vs baseline: 2.0615x; 2.0615x over previous
//
#include <hip/hip_runtime.h>
#include <math.h>

#define N_NODES 50000
#define N_EDGES 800000
#define FEAT    16
#define HID     64
#define KORD    32
#define NCLS    8

// W[d,k,f,c] flat index = (d*KORD + k)*80*64 + f*64 + c ; only rows f<16 matter (H0==0).
#define WSL     5120   // 80*64, per-(d,k) slice stride in floats

static constexpr size_t Aln(size_t x) { return (x + 255) & ~size_t(255); }

// ---- workspace layout (bytes) ----
static constexpr size_t OFF_DEG_OUT = 0;
static constexpr size_t OFF_DEG_IN  = OFF_DEG_OUT + Aln(N_NODES * 4);
static constexpr size_t OFF_CUR_DST = OFF_DEG_IN  + Aln(N_NODES * 4);
static constexpr size_t OFF_CUR_SRC = OFF_CUR_DST + Aln(N_NODES * 4);
static constexpr size_t ZERO_BYTES  = OFF_CUR_SRC + Aln(N_NODES * 4);   // zero [0, ZERO_BYTES)
static constexpr size_t OFF_OFF_DST = ZERO_BYTES;
static constexpr size_t OFF_OFF_SRC = OFF_OFF_DST + Aln((N_NODES + 1) * 4);
static constexpr size_t OFF_CSRD    = OFF_OFF_SRC + Aln((N_NODES + 1) * 4);  // int2{src, w_bits}
static constexpr size_t OFF_CSRS    = OFF_CSRD + Aln(N_EDGES * 8);           // int2{dst, w_bits}
static constexpr size_t OFF_TO0     = OFF_CSRS + Aln(N_EDGES * 8);
static constexpr size_t OFF_TO1     = OFF_TO0 + Aln(N_NODES * FEAT * 4);
static constexpr size_t OFF_TI0     = OFF_TO1 + Aln(N_NODES * FEAT * 4);
static constexpr size_t OFF_TI1     = OFF_TI0 + Aln(N_NODES * FEAT * 4);
static constexpr size_t OFF_HZ      = OFF_TI1 + Aln(N_NODES * FEAT * 4);
static constexpr size_t OFF_HH      = OFF_HZ  + Aln(N_NODES * HID * 4);
// total ~40 MB

__global__ void count_deg_kernel(const int* __restrict__ ei,
                                 int* __restrict__ deg_out, int* __restrict__ deg_in) {
    int e = blockIdx.x * blockDim.x + threadIdx.x;
    if (e < N_EDGES) {
        atomicAdd(&deg_out[ei[e]], 1);
        atomicAdd(&deg_in[ei[N_EDGES + e]], 1);
    }
}

// two exclusive scans (one block each): block 0: degA->offA, block 1: degB->offB
__global__ __launch_bounds__(1024) void scan_kernel(const int* __restrict__ degA, int* __restrict__ offA,
                                                    const int* __restrict__ degB, int* __restrict__ offB) {
    const int* deg = blockIdx.x ? degB : degA;
    int* off = blockIdx.x ? offB : offA;
    __shared__ int wsum[16];
    __shared__ int s_run;
    const int t = threadIdx.x, lane = t & 63, wid = t >> 6;
    if (t == 0) s_run = 0;
    __syncthreads();
    for (int base = 0; base < N_NODES; base += 1024) {
        int i = base + t;
        int v = (i < N_NODES) ? deg[i] : 0;
        int xv = v;
        #pragma unroll
        for (int d = 1; d < 64; d <<= 1) {
            int tt = __shfl_up(xv, d, 64);
            if (lane >= d) xv += tt;
        }
        if (lane == 63) wsum[wid] = xv;
        __syncthreads();
        int add = s_run;
        for (int w = 0; w < wid; ++w) add += wsum[w];
        if (i < N_NODES) off[i] = add + xv - v;   // exclusive
        __syncthreads();
        if (t == 1023) s_run = add + xv;
        __syncthreads();
    }
    if (t == 0) off[N_NODES] = s_run;
}

__global__ void fill_csr_kernel(const int* __restrict__ ei,
                                const int* __restrict__ deg_out, const int* __restrict__ deg_in,
                                const int* __restrict__ off_dst, const int* __restrict__ off_src,
                                int* __restrict__ cur_dst, int* __restrict__ cur_src,
                                int2* __restrict__ csrd, int2* __restrict__ csrs) {
    int e = blockIdx.x * blockDim.x + threadIdx.x;
    if (e >= N_EDGES) return;
    int s = ei[e], d = ei[N_EDGES + e];
    int p = off_dst[d] + atomicAdd(&cur_dst[d], 1);
    csrd[p] = make_int2(s, __float_as_int(1.0f / (float)deg_out[s]));  // norm_out = 1/deg_out[src]
    int q = off_src[s] + atomicAdd(&cur_src[s], 1);
    csrs[q] = make_int2(d, __float_as_int(1.0f / (float)deg_in[d]));   // norm_in = 1/deg_in[dst]
}

// gather helper: 16-lane node group, lane = (u=edge-sub 0..3, fq=float4-chunk 0..3)
// returns per-lane partial float4; caller reduces across u via shfl_xor(4,8).
__device__ __forceinline__ float4 gather4(const int2* __restrict__ csr, int beg, int end,
                                          int u, int fq, const float* __restrict__ src) {
    float4 acc = {0.f, 0.f, 0.f, 0.f};
    for (int e0 = beg; e0 < end; e0 += 8) {
        int eA = e0 + u, eB = e0 + 4 + u;
        int sA = 0, sB = 0;
        float wA = 0.f, wB = 0.f;
        if (eA < end) { int2 p = csr[eA]; sA = p.x; wA = __int_as_float(p.y); }
        if (eB < end) { int2 p = csr[eB]; sB = p.x; wB = __int_as_float(p.y); }
        float4 rA = *(const float4*)&src[sA * FEAT + fq * 4];
        float4 rB = *(const float4*)&src[sB * FEAT + fq * 4];
        acc.x += wA * rA.x + wB * rB.x;
        acc.y += wA * rA.y + wB * rB.y;
        acc.z += wA * rA.z + wB * rB.z;
        acc.w += wA * rA.w + wB * rB.w;
    }
    return acc;
}

__device__ __forceinline__ float4 reduce_u(float4 a) {
    a.x += __shfl_xor(a.x, 4); a.y += __shfl_xor(a.y, 4);
    a.z += __shfl_xor(a.z, 4); a.w += __shfl_xor(a.w, 4);
    a.x += __shfl_xor(a.x, 8); a.y += __shfl_xor(a.y, 8);
    a.z += __shfl_xor(a.z, 8); a.w += __shfl_xor(a.w, 8);
    return a;
}

// k=0,1 terms: T1o/T1i = P(x); Hz/Hh = b + x@(W[0,0]+W[1,0]) + T1o@W[0,1] + T1i@W[1,1]
__global__ __launch_bounds__(256) void init_kernel(
    const float* __restrict__ x,
    const int* __restrict__ off_dst, const int2* __restrict__ csrd,
    const int* __restrict__ off_src, const int2* __restrict__ csrs,
    const float* __restrict__ Wz, const float* __restrict__ bz,
    const float* __restrict__ Wh, const float* __restrict__ bh,
    float* __restrict__ T1o, float* __restrict__ T1i,
    float* __restrict__ Hz, float* __restrict__ Hh) {
    __shared__ float s_x[16][16], s_to[16][16], s_ti[16][16];
    __shared__ float sWz0s[1024], sWz1o[1024], sWz1i[1024];
    __shared__ float sWh0s[1024], sWh1o[1024], sWh1i[1024];
    const int t = threadIdx.x;
    for (int j = t; j < 1024; j += 256) {
        sWz0s[j] = Wz[j] + Wz[KORD * WSL + j];
        sWz1o[j] = Wz[WSL + j];
        sWz1i[j] = Wz[KORD * WSL + WSL + j];
        sWh0s[j] = Wh[j] + Wh[KORD * WSL + j];
        sWh1o[j] = Wh[WSL + j];
        sWh1i[j] = Wh[KORD * WSL + WSL + j];
    }
    const int g = t >> 4, l = t & 15, u = l >> 2, fq = l & 3;
    const int i = blockIdx.x * 16 + g;
    const int bD = off_dst[i], eD = off_dst[i + 1];
    const int bS = off_src[i], eS = off_src[i + 1];
    float4 aO = reduce_u(gather4(csrd, bD, eD, u, fq, x));
    float4 aI = reduce_u(gather4(csrs, bS, eS, u, fq, x));
    if (u == 0) {
        float4 xr = *(const float4*)&x[i * FEAT + fq * 4];
        *(float4*)&s_x[g][fq * 4] = xr;
        *(float4*)&T1o[i * FEAT + fq * 4] = aO;
        *(float4*)&s_to[g][fq * 4] = aO;
        *(float4*)&T1i[i * FEAT + fq * 4] = aI;
        *(float4*)&s_ti[g][fq * 4] = aI;
    }
    __syncthreads();
    const int n2 = t >> 4, c0 = (t & 15) * 4;
    float4 hz = *(const float4*)&bz[c0];
    float4 hh = *(const float4*)&bh[c0];
    #pragma unroll
    for (int ff = 0; ff < 16; ++ff) {
        float xvv = s_x[n2][ff], to = s_to[n2][ff], ti = s_ti[n2][ff];
        float4 wz0 = *(const float4*)&sWz0s[ff * 64 + c0];
        float4 wz1 = *(const float4*)&sWz1o[ff * 64 + c0];
        float4 wz2 = *(const float4*)&sWz1i[ff * 64 + c0];
        float4 wh0 = *(const float4*)&sWh0s[ff * 64 + c0];
        float4 wh1 = *(const float4*)&sWh1o[ff * 64 + c0];
        float4 wh2 = *(const float4*)&sWh1i[ff * 64 + c0];
        hz.x += xvv * wz0.x + to * wz1.x + ti * wz2.x;
        hz.y += xvv * wz0.y + to * wz1.y + ti * wz2.y;
        hz.z += xvv * wz0.z + to * wz1.z + ti * wz2.z;
        hz.w += xvv * wz0.w + to * wz1.w + ti * wz2.w;
        hh.x += xvv * wh0.x + to * wh1.x + ti * wh2.x;
        hh.y += xvv * wh0.y + to * wh1.y + ti * wh2.y;
        hh.z += xvv * wh0.z + to * wh1.z + ti * wh2.z;
        hh.w += xvv * wh0.w + to * wh1.w + ti * wh2.w;
    }
    const int i2 = blockIdx.x * 16 + n2;
    *(float4*)&Hz[i2 * 64 + c0] = hz;
    *(float4*)&Hh[i2 * 64 + c0] = hh;
}

// one Chebyshev step k (2..31): T_k = 2*P*T_{k-1} - T_{k-2} (both dirs) + accumulate Hz/Hh
__global__ __launch_bounds__(256) void step_kernel(
    const int* __restrict__ off_dst, const int2* __restrict__ csrd,
    const int* __restrict__ off_src, const int2* __restrict__ csrs,
    const float* __restrict__ prevO, const float* __restrict__ ppO, float* __restrict__ outO,
    const float* __restrict__ prevI, const float* __restrict__ ppI, float* __restrict__ outI,
    const float* __restrict__ Wz, const float* __restrict__ Wh, int k,
    float* __restrict__ Hz, float* __restrict__ Hh) {
    __shared__ float s_to[16][16], s_ti[16][16];
    __shared__ float sWz0[1024], sWz1[1024], sWh0[1024], sWh1[1024];
    const int t = threadIdx.x;
    const int b0 = k * WSL, b1 = (KORD + k) * WSL;
    for (int j = t; j < 1024; j += 256) {
        sWz0[j] = Wz[b0 + j]; sWz1[j] = Wz[b1 + j];
        sWh0[j] = Wh[b0 + j]; sWh1[j] = Wh[b1 + j];
    }
    const int g = t >> 4, l = t & 15, u = l >> 2, fq = l & 3;
    const int i = blockIdx.x * 16 + g;
    const int bD = off_dst[i], eD = off_dst[i + 1];
    const int bS = off_src[i], eS = off_src[i + 1];
    float4 aO = reduce_u(gather4(csrd, bD, eD, u, fq, prevO));
    float4 aI = reduce_u(gather4(csrs, bS, eS, u, fq, prevI));
    if (u == 0) {
        float4 pO = *(const float4*)&ppO[i * FEAT + fq * 4];
        float4 pI = *(const float4*)&ppI[i * FEAT + fq * 4];
        float4 t2o, t2i;
        t2o.x = 2.f * aO.x - pO.x; t2o.y = 2.f * aO.y - pO.y;
        t2o.z = 2.f * aO.z - pO.z; t2o.w = 2.f * aO.w - pO.w;
        t2i.x = 2.f * aI.x - pI.x; t2i.y = 2.f * aI.y - pI.y;
        t2i.z = 2.f * aI.z - pI.z; t2i.w = 2.f * aI.w - pI.w;
        *(float4*)&outO[i * FEAT + fq * 4] = t2o;
        *(float4*)&s_to[g][fq * 4] = t2o;
        *(float4*)&outI[i * FEAT + fq * 4] = t2i;
        *(float4*)&s_ti[g][fq * 4] = t2i;
    }
    __syncthreads();
    const int n2 = t >> 4, c0 = (t & 15) * 4;
    float4 hz = {0.f, 0.f, 0.f, 0.f}, hh = {0.f, 0.f, 0.f, 0.f};
    #pragma unroll
    for (int ff = 0; ff < 16; ++ff) {
        float to = s_to[n2][ff], ti = s_ti[n2][ff];
        float4 wz0 = *(const float4*)&sWz0[ff * 64 + c0];
        float4 wz1 = *(const float4*)&sWz1[ff * 64 + c0];
        float4 wh0 = *(const float4*)&sWh0[ff * 64 + c0];
        float4 wh1 = *(const float4*)&sWh1[ff * 64 + c0];
        hz.x += to * wz0.x + ti * wz1.x;
        hz.y += to * wz0.y + ti * wz1.y;
        hz.z += to * wz0.z + ti * wz1.z;
        hz.w += to * wz0.w + ti * wz1.w;
        hh.x += to * wh0.x + ti * wh1.x;
        hh.y += to * wh0.y + ti * wh1.y;
        hh.z += to * wh0.z + ti * wh1.z;
        hh.w += to * wh0.w + ti * wh1.w;
    }
    const int i2 = blockIdx.x * 16 + n2;
    float4* hzp = (float4*)&Hz[i2 * 64 + c0];
    float4 v = *hzp;
    v.x += hz.x; v.y += hz.y; v.z += hz.z; v.w += hz.w;
    *hzp = v;
    float4* hhp = (float4*)&Hh[i2 * 64 + c0];
    float4 w = *hhp;
    w.x += hh.x; w.y += hh.y; w.z += hh.z; w.w += hh.w;
    *hhp = w;
}

// H = (1-sigmoid(Hz))*tanh(Hh); out = relu(H) @ lin_w + lin_b
__global__ __launch_bounds__(256) void final_kernel(
    const float* __restrict__ Hz, const float* __restrict__ Hh,
    const float* __restrict__ lin_w, const float* __restrict__ lin_b,
    float* __restrict__ out) {
    __shared__ float s_h[32][65];
    const int t = threadIdx.x;
    const int base = blockIdx.x * 32;
    #pragma unroll
    for (int r = 0; r < 8; ++r) {
        int idx = r * 256 + t;
        int n = idx >> 6, h = idx & 63;
        int i = base + n;
        float v = 0.f;
        if (i < N_NODES) {
            float z = 1.f / (1.f + __expf(-Hz[i * 64 + h]));
            float ht = tanhf(Hh[i * 64 + h]);
            v = fmaxf(0.f, (1.f - z) * ht);
        }
        s_h[n][h] = v;
    }
    __syncthreads();
    int n = t >> 3, c = t & 7;
    int i = base + n;
    if (i < N_NODES) {
        float acc = lin_b[c];
        #pragma unroll
        for (int h = 0; h < 64; ++h) acc += s_h[n][h] * lin_w[h * 8 + c];
        out[i * NCLS + c] = acc;
    }
}

extern "C" void kernel_launch(void* const* d_in, const int* in_sizes, int n_in,
                              void* d_out, int out_size, void* d_ws, size_t ws_size,
                              hipStream_t stream) {
    const float* x   = (const float*)d_in[0];
    const int*   ei  = (const int*)d_in[1];
    const float* Wz  = (const float*)d_in[2];
    const float* bz  = (const float*)d_in[3];
    // d_in[4] = W_r, d_in[5] = b_r : unused (H0 == 0 makes R irrelevant)
    const float* Wh  = (const float*)d_in[6];
    const float* bh  = (const float*)d_in[7];
    const float* lw  = (const float*)d_in[8];
    const float* lb  = (const float*)d_in[9];
    float* out = (float*)d_out;
    char* ws = (char*)d_ws;

    int*  deg_out = (int*)(ws + OFF_DEG_OUT);
    int*  deg_in  = (int*)(ws + OFF_DEG_IN);
    int*  cur_dst = (int*)(ws + OFF_CUR_DST);
    int*  cur_src = (int*)(ws + OFF_CUR_SRC);
    int*  off_dst = (int*)(ws + OFF_OFF_DST);
    int*  off_src = (int*)(ws + OFF_OFF_SRC);
    int2* csrd    = (int2*)(ws + OFF_CSRD);
    int2* csrs    = (int2*)(ws + OFF_CSRS);
    float* To0 = (float*)(ws + OFF_TO0);
    float* To1 = (float*)(ws + OFF_TO1);
    float* Ti0 = (float*)(ws + OFF_TI0);
    float* Ti1 = (float*)(ws + OFF_TI1);
    float* Hz  = (float*)(ws + OFF_HZ);
    float* Hh  = (float*)(ws + OFF_HH);

    hipMemsetAsync(ws, 0, ZERO_BYTES, stream);

    const int EB = (N_EDGES + 255) / 256;       // 3125
    const int NB16 = N_NODES / 16;              // 3125 (exact)
    count_deg_kernel<<<EB, 256, 0, stream>>>(ei, deg_out, deg_in);
    scan_kernel<<<2, 1024, 0, stream>>>(deg_in, off_dst, deg_out, off_src);
    fill_csr_kernel<<<EB, 256, 0, stream>>>(ei, deg_out, deg_in, off_dst, off_src,
                                            cur_dst, cur_src, csrd, csrs);
    init_kernel<<<NB16, 256, 0, stream>>>(x, off_dst, csrd, off_src, csrs,
                                          Wz, bz, Wh, bh, To1, Ti1, Hz, Hh);
    const float* pO = To1;
    const float* pI = Ti1;
    for (int k = 2; k < KORD; ++k) {
        float* oO = (k & 1) ? To1 : To0;
        float* oI = (k & 1) ? Ti1 : Ti0;
        const float* qO = (k == 2) ? x : (const float*)oO;  // T_{k-2} aliases out buffer (elementwise-safe)
        const float* qI = (k == 2) ? x : (const float*)oI;
        step_kernel<<<NB16, 256, 0, stream>>>(off_dst, csrd, off_src, csrs,
                                              pO, qO, oO, pI, qI, oI, Wz, Wh, k, Hz, Hh);
        pO = oO; pI = oI;
    }
    final_kernel<<<(N_NODES + 31) / 32, 256, 0, stream>>>(Hz, Hh, lw, lb, out);
}

// Round 4
// 1145.011 us; speedup vs baseline: 2.5703x; 1.2468x over previous
//
#include <hip/hip_runtime.h>
#include <math.h>

#define N_NODES 50000
#define N_EDGES 800000
#define FEAT    16
#define HID     64
#define KORD    32
#define NCLS    8

// W[d,k,f,c] flat index = (d*KORD + k)*80*64 + f*64 + c ; only rows f<16 matter (H0==0).
#define WSL     5120   // 80*64, per-(d,k) slice stride in floats
#define SLOT    (N_NODES * FEAT)   // 800000 floats per slab slot

static constexpr size_t Aln(size_t x) { return (x + 255) & ~size_t(255); }

// ---- workspace layout (bytes), total ~59.3 MB ----
static constexpr size_t OFF_DEG_OUT = 0;
static constexpr size_t OFF_DEG_IN  = OFF_DEG_OUT + Aln(N_NODES * 4);
static constexpr size_t OFF_CUR_DST = OFF_DEG_IN  + Aln(N_NODES * 4);
static constexpr size_t OFF_CUR_SRC = OFF_CUR_DST + Aln(N_NODES * 4);
static constexpr size_t ZERO_BYTES  = OFF_CUR_SRC + Aln(N_NODES * 4);   // zero [0, ZERO_BYTES)
static constexpr size_t OFF_OFF_DST = ZERO_BYTES;
static constexpr size_t OFF_OFF_SRC = OFF_OFF_DST + Aln((N_NODES + 1) * 4);
static constexpr size_t OFF_CSRD    = OFF_OFF_SRC + Aln((N_NODES + 1) * 4);  // uint{deg:16|idx:16}
static constexpr size_t OFF_CSRS    = OFF_CSRD + Aln(N_EDGES * 4);
static constexpr size_t OFF_HZ      = OFF_CSRS + Aln(N_EDGES * 4);
static constexpr size_t OFF_HH      = OFF_HZ  + Aln(N_NODES * HID * 4);
static constexpr size_t OFF_SLAB    = OFF_HH  + Aln(N_NODES * HID * 4);      // 8 slots f32
static constexpr size_t OFF_WCAT    = OFF_SLAB + Aln((size_t)8 * SLOT * 4);
static constexpr size_t WS_TOTAL    = OFF_WCAT + Aln((size_t)64 * 16 * 128 * 4);

__global__ void count_deg_kernel(const int* __restrict__ ei,
                                 int* __restrict__ deg_out, int* __restrict__ deg_in) {
    int e = blockIdx.x * blockDim.x + threadIdx.x;
    if (e < N_EDGES) {
        atomicAdd(&deg_out[ei[e]], 1);
        atomicAdd(&deg_in[ei[N_EDGES + e]], 1);
    }
}

// two exclusive scans (one block each): block 0: degA->offA, block 1: degB->offB
__global__ __launch_bounds__(1024) void scan_kernel(const int* __restrict__ degA, int* __restrict__ offA,
                                                    const int* __restrict__ degB, int* __restrict__ offB) {
    const int* deg = blockIdx.x ? degB : degA;
    int* off = blockIdx.x ? offB : offA;
    __shared__ int wsum[16];
    __shared__ int s_run;
    const int t = threadIdx.x, lane = t & 63, wid = t >> 6;
    if (t == 0) s_run = 0;
    __syncthreads();
    for (int base = 0; base < N_NODES; base += 1024) {
        int i = base + t;
        int v = (i < N_NODES) ? deg[i] : 0;
        int xv = v;
        #pragma unroll
        for (int d = 1; d < 64; d <<= 1) {
            int tt = __shfl_up(xv, d, 64);
            if (lane >= d) xv += tt;
        }
        if (lane == 63) wsum[wid] = xv;
        __syncthreads();
        int add = s_run;
        for (int w = 0; w < wid; ++w) add += wsum[w];
        if (i < N_NODES) off[i] = add + xv - v;   // exclusive
        __syncthreads();
        if (t == 1023) s_run = add + xv;
        __syncthreads();
    }
    if (t == 0) off[N_NODES] = s_run;
}

__global__ void fill_csr_kernel(const int* __restrict__ ei,
                                const int* __restrict__ deg_out, const int* __restrict__ deg_in,
                                const int* __restrict__ off_dst, const int* __restrict__ off_src,
                                int* __restrict__ cur_dst, int* __restrict__ cur_src,
                                unsigned int* __restrict__ csrd, unsigned int* __restrict__ csrs) {
    int e = blockIdx.x * blockDim.x + threadIdx.x;
    if (e >= N_EDGES) return;
    int s = ei[e], d = ei[N_EDGES + e];
    // packed entry: {deg:16 | idx:16}; weight computed in-gather as exact 1.0f/deg
    int p = off_dst[d] + atomicAdd(&cur_dst[d], 1);
    csrd[p] = ((unsigned int)deg_out[s] << 16) | (unsigned int)s;  // w = 1/deg_out[src]
    int q = off_src[s] + atomicAdd(&cur_src[s], 1);
    csrs[q] = ((unsigned int)deg_in[d] << 16) | (unsigned int)d;   // w = 1/deg_in[dst]
}

// gather: 16-lane node group, lane = (u=edge-sub 0..3, fq=float4-chunk 0..3), 16 edges/iter.
__device__ __forceinline__ float4 gather4d(const unsigned int* __restrict__ csr, int beg, int end,
                                           int u, int fq, const float* __restrict__ src) {
    float4 acc = {0.f, 0.f, 0.f, 0.f};
    for (int e0 = beg; e0 < end; e0 += 16) {
        int ea = e0 + u, eb = e0 + 4 + u, ec = e0 + 8 + u, ed = e0 + 12 + u;
        unsigned int pa = (ea < end) ? csr[ea] : 0x10000u;   // pad: deg=1, idx=0
        unsigned int pb = (eb < end) ? csr[eb] : 0x10000u;
        unsigned int pc = (ec < end) ? csr[ec] : 0x10000u;
        unsigned int pd = (ed < end) ? csr[ed] : 0x10000u;
        float wa = (ea < end) ? 1.0f / (float)(pa >> 16) : 0.0f;  // exact IEEE div, matches ref
        float wb = (eb < end) ? 1.0f / (float)(pb >> 16) : 0.0f;
        float wc = (ec < end) ? 1.0f / (float)(pc >> 16) : 0.0f;
        float wd = (ed < end) ? 1.0f / (float)(pd >> 16) : 0.0f;
        const float4 ra = *(const float4*)&src[(pa & 0xFFFFu) * FEAT + fq * 4];
        const float4 rb = *(const float4*)&src[(pb & 0xFFFFu) * FEAT + fq * 4];
        const float4 rc = *(const float4*)&src[(pc & 0xFFFFu) * FEAT + fq * 4];
        const float4 rd = *(const float4*)&src[(pd & 0xFFFFu) * FEAT + fq * 4];
        acc.x += wa * ra.x + wb * rb.x + wc * rc.x + wd * rd.x;
        acc.y += wa * ra.y + wb * rb.y + wc * rc.y + wd * rd.y;
        acc.z += wa * ra.z + wb * rb.z + wc * rc.z + wd * rd.z;
        acc.w += wa * ra.w + wb * rb.w + wc * rc.w + wd * rd.w;
    }
    return acc;
}

__device__ __forceinline__ float4 reduce_u(float4 a) {
    a.x += __shfl_xor(a.x, 4); a.y += __shfl_xor(a.y, 4);
    a.z += __shfl_xor(a.z, 4); a.w += __shfl_xor(a.w, 4);
    a.x += __shfl_xor(a.x, 8); a.y += __shfl_xor(a.y, 8);
    a.z += __shfl_xor(a.z, 8); a.w += __shfl_xor(a.w, 8);
    return a;
}

// k=0,1: slab slots (f32): 0 = x, 1 = T1o, 4 = x, 5 = T1i
__global__ __launch_bounds__(256) void init_kernel(
    const float* __restrict__ x,
    const int* __restrict__ off_dst, const unsigned int* __restrict__ csrd,
    const int* __restrict__ off_src, const unsigned int* __restrict__ csrs,
    float* __restrict__ slab) {
    const int t = threadIdx.x;
    const int g = t >> 4, l = t & 15, u = l >> 2, fq = l & 3;
    const int i = blockIdx.x * 16 + g;
    const int bD = off_dst[i], eD = off_dst[i + 1];
    const int bS = off_src[i], eS = off_src[i + 1];
    float4 aO = reduce_u(gather4d(csrd, bD, eD, u, fq, x));
    float4 aI = reduce_u(gather4d(csrs, bS, eS, u, fq, x));
    if (u == 0) {
        const int ro = i * FEAT + fq * 4;
        float4 xr = *(const float4*)&x[ro];
        *(float4*)&slab[0 * SLOT + ro] = xr;   // T0 (dir O)
        *(float4*)&slab[4 * SLOT + ro] = xr;   // T0 (dir I)
        *(float4*)&slab[1 * SLOT + ro] = aO;   // T1o
        *(float4*)&slab[5 * SLOT + ro] = aI;   // T1i
    }
}

// Chebyshev step k: T_k = 2*P*T_{k-1} - T_{k-2} (both dirs); slab slots serve as ping-pong.
__global__ __launch_bounds__(256) void step_kernel(
    const int* __restrict__ off_dst, const unsigned int* __restrict__ csrd,
    const int* __restrict__ off_src, const unsigned int* __restrict__ csrs,
    const float* __restrict__ prevO, const float* __restrict__ ppO, float* __restrict__ outO,
    const float* __restrict__ prevI, const float* __restrict__ ppI, float* __restrict__ outI) {
    const int t = threadIdx.x;
    const int g = t >> 4, l = t & 15, u = l >> 2, fq = l & 3;
    const int i = blockIdx.x * 16 + g;
    const int bD = off_dst[i], eD = off_dst[i + 1];
    const int bS = off_src[i], eS = off_src[i + 1];
    float4 aO = reduce_u(gather4d(csrd, bD, eD, u, fq, prevO));
    float4 aI = reduce_u(gather4d(csrs, bS, eS, u, fq, prevI));
    if (u == 0) {
        const int ro = i * FEAT + fq * 4;
        float4 pO = *(const float4*)&ppO[ro];
        float4 pI = *(const float4*)&ppI[ro];
        float4 t2o, t2i;
        t2o.x = 2.f * aO.x - pO.x; t2o.y = 2.f * aO.y - pO.y;
        t2o.z = 2.f * aO.z - pO.z; t2o.w = 2.f * aO.w - pO.w;
        t2i.x = 2.f * aI.x - pI.x; t2i.y = 2.f * aI.y - pI.y;
        t2i.z = 2.f * aI.z - pI.z; t2i.w = 2.f * aI.w - pI.w;
        *(float4*)&outO[ro] = t2o;
        *(float4*)&outI[ro] = t2i;
    }
}

// Wcat[s][f][c] f32: s=d*32+k; c<64 -> Wz, c>=64 -> Wh (rows f<16 only)
__global__ void wcat_kernel(const float* __restrict__ Wz, const float* __restrict__ Wh,
                            float* __restrict__ wcat) {
    int idx = blockIdx.x * blockDim.x + threadIdx.x;   // 64*16*128
    if (idx >= 64 * 16 * 128) return;
    int s = idx >> 11, f = (idx >> 7) & 15, c = idx & 127;
    float v = (c < 64) ? Wz[s * WSL + f * 64 + c] : Wh[s * WSL + f * 64 + (c - 64)];
    wcat[idx] = v;
}

// batched GEMM over one 4-k batch: Hz|Hh[node,c] (+)= sum over 8 slots (si<4 dir0, si>=4 dir1)
// of slab[si][node][f] * wcat[(si>>2)*32 + b4 + (si&3)][f][c].  M-tile 128, N=128, 8x8/thread.
__global__ __launch_bounds__(256) void gemm_kernel(
    const float* __restrict__ slab, const float* __restrict__ wcat,
    const float* __restrict__ bz, const float* __restrict__ bh,
    float* __restrict__ Hz, float* __restrict__ Hh, int b4, int first) {
    __shared__ float As[128][20];    // stride 20 keeps float4 stores 16B-aligned
    __shared__ float Ws[16][132];
    const int t = threadIdx.x;
    const int tx = t & 15, ty = t >> 4;
    const int node0 = blockIdx.x * 128;
    float acc[8][8];
    #pragma unroll
    for (int j = 0; j < 8; ++j)
        #pragma unroll
        for (int i = 0; i < 8; ++i) acc[j][i] = 0.f;

    for (int si = 0; si < 8; ++si) {
        // load A: 128 nodes x 16 f32 (512 float4s, 2 per thread)
        #pragma unroll
        for (int it = 0; it < 2; ++it) {
            int id = t + 256 * it;
            int r = id >> 2, q = id & 3;
            int node = node0 + r;
            float4 v = make_float4(0.f, 0.f, 0.f, 0.f);
            if (node < N_NODES) v = *(const float4*)&slab[(size_t)si * SLOT + node * FEAT + q * 4];
            *(float4*)&As[r][q * 4] = v;
        }
        // load W slice: 16 x 128 f32
        {
            int sg = (si >> 2) * 32 + b4 + (si & 3);
            const float* wsrc = wcat + (size_t)sg * 2048;
            int idx = t * 8;
            int kk = idx >> 7, c = idx & 127;
            *(float4*)&Ws[kk][c]     = *(const float4*)&wsrc[kk * 128 + c];
            *(float4*)&Ws[kk][c + 4] = *(const float4*)&wsrc[kk * 128 + c + 4];
        }
        __syncthreads();
        #pragma unroll
        for (int kk = 0; kk < 16; ++kk) {
            float a[8], w[8];
            #pragma unroll
            for (int j = 0; j < 8; ++j) a[j] = As[ty + 16 * j][kk];
            #pragma unroll
            for (int i = 0; i < 8; ++i) w[i] = Ws[kk][tx + 16 * i];
            #pragma unroll
            for (int j = 0; j < 8; ++j)
                #pragma unroll
                for (int i = 0; i < 8; ++i) acc[j][i] += a[j] * w[i];
        }
        __syncthreads();
    }
    // epilogue: cols 0..63 -> Hz, 64..127 -> Hh
    #pragma unroll
    for (int j = 0; j < 8; ++j) {
        int node = node0 + ty + 16 * j;
        if (node >= N_NODES) continue;
        #pragma unroll
        for (int i = 0; i < 4; ++i) {
            int c = tx + 16 * i;
            float* p = &Hz[(size_t)node * 64 + c];
            *p = first ? (bz[c] + acc[j][i]) : (*p + acc[j][i]);
        }
        #pragma unroll
        for (int i = 4; i < 8; ++i) {
            int c = tx + 16 * (i - 4);
            float* p = &Hh[(size_t)node * 64 + c];
            *p = first ? (bh[c] + acc[j][i]) : (*p + acc[j][i]);
        }
    }
}

// H = (1-sigmoid(Hz))*tanh(Hh); out = relu(H) @ lin_w + lin_b
__global__ __launch_bounds__(256) void final_kernel(
    const float* __restrict__ Hz, const float* __restrict__ Hh,
    const float* __restrict__ lin_w, const float* __restrict__ lin_b,
    float* __restrict__ out) {
    __shared__ float s_h[32][65];
    const int t = threadIdx.x;
    const int base = blockIdx.x * 32;
    #pragma unroll
    for (int r = 0; r < 8; ++r) {
        int idx = r * 256 + t;
        int n = idx >> 6, h = idx & 63;
        int i = base + n;
        float v = 0.f;
        if (i < N_NODES) {
            float z = 1.f / (1.f + __expf(-Hz[i * 64 + h]));
            float ht = tanhf(Hh[i * 64 + h]);
            v = fmaxf(0.f, (1.f - z) * ht);
        }
        s_h[n][h] = v;
    }
    __syncthreads();
    int n = t >> 3, c = t & 7;
    int i = base + n;
    if (i < N_NODES) {
        float acc = lin_b[c];
        #pragma unroll
        for (int h = 0; h < 64; ++h) acc += s_h[n][h] * lin_w[h * 8 + c];
        out[i * NCLS + c] = acc;
    }
}

extern "C" void kernel_launch(void* const* d_in, const int* in_sizes, int n_in,
                              void* d_out, int out_size, void* d_ws, size_t ws_size,
                              hipStream_t stream) {
    const float* x   = (const float*)d_in[0];
    const int*   ei  = (const int*)d_in[1];
    const float* Wz  = (const float*)d_in[2];
    const float* bz  = (const float*)d_in[3];
    // d_in[4] = W_r, d_in[5] = b_r : unused (H0 == 0 makes R irrelevant)
    const float* Wh  = (const float*)d_in[6];
    const float* bh  = (const float*)d_in[7];
    const float* lw  = (const float*)d_in[8];
    const float* lb  = (const float*)d_in[9];
    float* out = (float*)d_out;
    char* ws = (char*)d_ws;

    int*  deg_out = (int*)(ws + OFF_DEG_OUT);
    int*  deg_in  = (int*)(ws + OFF_DEG_IN);
    int*  cur_dst = (int*)(ws + OFF_CUR_DST);
    int*  cur_src = (int*)(ws + OFF_CUR_SRC);
    int*  off_dst = (int*)(ws + OFF_OFF_DST);
    int*  off_src = (int*)(ws + OFF_OFF_SRC);
    unsigned int* csrd = (unsigned int*)(ws + OFF_CSRD);
    unsigned int* csrs = (unsigned int*)(ws + OFF_CSRS);
    float* Hz   = (float*)(ws + OFF_HZ);
    float* Hh   = (float*)(ws + OFF_HH);
    float* slab = (float*)(ws + OFF_SLAB);
    float* wcat = (float*)(ws + OFF_WCAT);

    hipMemsetAsync(ws, 0, ZERO_BYTES, stream);

    const int EB = (N_EDGES + 255) / 256;       // 3125
    const int NB16 = N_NODES / 16;              // 3125 (exact)
    count_deg_kernel<<<EB, 256, 0, stream>>>(ei, deg_out, deg_in);
    scan_kernel<<<2, 1024, 0, stream>>>(deg_in, off_dst, deg_out, off_src);
    fill_csr_kernel<<<EB, 256, 0, stream>>>(ei, deg_out, deg_in, off_dst, off_src,
                                            cur_dst, cur_src, csrd, csrs);
    wcat_kernel<<<(64 * 16 * 128 + 255) / 256, 256, 0, stream>>>(Wz, Wh, wcat);
    init_kernel<<<NB16, 256, 0, stream>>>(x, off_dst, csrd, off_src, csrs, slab);

    for (int k = 2; k < KORD; ++k) {
        const float* prevO = slab + (size_t)(((k - 1) & 3)) * SLOT;
        const float* ppO   = slab + (size_t)(((k - 2) & 3)) * SLOT;
        float*       outO  = slab + (size_t)((k & 3)) * SLOT;
        const float* prevI = slab + (size_t)(4 + ((k - 1) & 3)) * SLOT;
        const float* ppI   = slab + (size_t)(4 + ((k - 2) & 3)) * SLOT;
        float*       outI  = slab + (size_t)(4 + (k & 3)) * SLOT;
        step_kernel<<<NB16, 256, 0, stream>>>(off_dst, csrd, off_src, csrs,
                                              prevO, ppO, outO, prevI, ppI, outI);
        if ((k & 3) == 3) {   // batch of 4 complete: slots 0..3 = T_{k-3..k} (O), 4..7 (I)
            gemm_kernel<<<(N_NODES + 127) / 128, 256, 0, stream>>>(
                slab, wcat, bz, bh, Hz, Hh, k - 3, (k == 3) ? 1 : 0);
        }
    }
    final_kernel<<<(N_NODES + 31) / 32, 256, 0, stream>>>(Hz, Hh, lw, lb, out);
}